// Round 15
// baseline (2441.999 us; speedup 1.0000x reference)
//
#include <hip/hip_runtime.h>
#include <math.h>

// ---------------------------------------------------------------------------
// Encoder_Cross: B=8,V=16,P=128,L=16,D=128, PD=2048.
// gemm256: R6 phase schedule with UNIFORM-DEPTH staging: all 4 half-tiles of
// tile t+2 staged same-buffer at P3 (B0,B1) and P4 (A0,A1); steady vmcnt(8).
// Legal because wave wn{0,1}/{2,3} reads only B0/B1 (last read P2) and wave
// wm reads only its own A half (last read P3).
// Glue: fused QKV, fused scores+softmax, residual chain through XB, 2-wave attn2.
// ---------------------------------------------------------------------------

using u16   = unsigned short;
using f32x4 = __attribute__((ext_vector_type(4))) float;
using bf16x8= __attribute__((ext_vector_type(8))) __bf16;
using u16x8 = __attribute__((ext_vector_type(8))) u16;
using u16x4 = __attribute__((ext_vector_type(4))) u16;

#define NROWS 16384   // B*V*P
#define PD    2048
#define MEMBAR asm volatile("" ::: "memory")

__device__ __forceinline__ float bf2f(u16 u) {
    unsigned v = ((unsigned)u) << 16;
    return __builtin_bit_cast(float, v);
}
__device__ __forceinline__ u16 f2bf(float f) {
    unsigned u = __builtin_bit_cast(unsigned, f);
    u += 0x7FFFu + ((u >> 16) & 1u);        // RNE
    return (u16)(u >> 16);
}
__device__ __forceinline__ void gload_lds16(const void* g, void* l) {
    __builtin_amdgcn_global_load_lds((const __attribute__((address_space(1))) void*)g,
                                     (__attribute__((address_space(3))) void*)l, 16, 0, 0);
}
__device__ __forceinline__ void block_barrier() {
    MEMBAR; __builtin_amdgcn_s_barrier(); MEMBAR;
}

// ---------------------------------------------------------------------------
// 256x256-tile NT GEMM:  C[m][n] = sum_k A[m][k]*B[n][k] + bias[n]
// Regions per buffer (16KB each): A0 @0, A1 @16384, B0 @32768, B1 @49152.
// Read footprint per tile t (buf = t&1):
//   P1: a-lo rows wm*128..+63 (wm0->A0, wm1->A1); b0 rows wn*64..+31
//       (wn01->B0, wn23->B1)
//   P2: b1 rows wn*64+32..+63 (wn01->B0, wn23->B1)   [B last read]
//   P3: a-hi rows wm*128+64..+127 (wm0->A0, wm1->A1) [A last read]
// Stages (same buffer, tile t+2): P3 after bar: B0,B1 (B freed at P2 bar);
// P4: A0,A1 (A freed at P3 bar).  Drain at P4: outstanding = 8 (t+1, from
// P3/P4 of t-1) + 8 (t+2, this tile) = 16; vmcnt(8) retires tile t+1 fully
// before P1(t+1).  Prologue: t0 (8 loads) + t1 (8 loads), drain to 8.
// ---------------------------------------------------------------------------
template<int GELU>
__global__ __launch_bounds__(512, 2)
void gemm256(const u16* __restrict__ A, int lda,
             const u16* __restrict__ B, int ldb,
             u16* __restrict__ C1, u16* __restrict__ C2, int ncut, int ldc,
             const float* __restrict__ bias1, const float* __restrict__ bias2,
             int K, int NT, int CM, int CN)
{
    __shared__ __align__(16) char smem[131072];

    const int tid  = threadIdx.x;
    const int wv   = tid >> 6;
    const int wm   = wv >> 2;          // 0..1
    const int wn   = wv & 3;           // 0..3
    const int lane = tid & 63;
    const int fr   = lane & 15;
    const int fks16= (lane >> 4) * 16;
    const int rmask= (fr & 7) << 4;
    const int kb0  = fks16 ^ rmask;
    const int kb1  = (64 + fks16) ^ rmask;

    const int xcd = blockIdx.x & 7;
    const int ii  = blockIdx.x >> 3;
    const int RY  = NT / CN;
    const int mt  = (xcd / RY) * CM + (ii / CN);
    const int nt  = (xcd % RY) * CN + (ii % CN);
    const int m0  = mt * 256;
    const int n0  = nt * 256;

    const int rsub = tid >> 3;
    const int cswE = (((tid & 7) * 16) ^ ((rsub & 7) << 4)) >> 1;
    const int waveByte = wv * 1024;

    auto stage = [&](const u16* mat, int ld, int row0, int k0, int regionByte) {
        const u16* g0 = mat + (size_t)(row0 + rsub) * ld + k0 + cswE;
        gload_lds16(g0,                   smem + regionByte + waveByte);
        gload_lds16(g0 + (size_t)ld * 64, smem + regionByte + 8192 + waveByte);
    };

    const int aRowByte = (wm * 128 + fr) * 128;
    const int bRowByte = (wn * 64 + fr) * 128;

    const int KT = K >> 6;

    // -------- prologue: t0 all 4 + t1 all 4; drain t0 --------
    stage(A, lda, m0,       0, 0);          // t0.A0
    stage(B, ldb, n0,       0, 32768);      // t0.B0
    stage(A, lda, m0 + 128, 0, 16384);      // t0.A1
    stage(B, ldb, n0 + 128, 0, 49152);      // t0.B1
    stage(B, ldb, n0,      64, 98304);      // t1.B0
    stage(B, ldb, n0 + 128,64, 114688);     // t1.B1
    stage(A, lda, m0,      64, 65536);      // t1.A0
    stage(A, lda, m0 + 128,64, 81920);      // t1.A1
    asm volatile("s_waitcnt vmcnt(8)" ::: "memory");
    __builtin_amdgcn_s_barrier();

    bf16x8 a[4][2], b0[2][2], b1[2][2];
    f32x4  acc[8][4] = {};

    for (int t = 0; t < KT; ++t) {
        const int Ab = (t & 1) ? 65536 : 0;
        const int Bb = Ab + 32768;
        const bool s1 = (t + 1 < KT), s2 = (t + 2 < KT);

        // ---- phase 1: read a-lo + b0 ----
        #pragma unroll
        for (int mi = 0; mi < 4; ++mi) {
            const int rb = Ab + aRowByte + mi * 2048;
            a[mi][0] = *(const bf16x8*)(smem + rb + kb0);
            a[mi][1] = *(const bf16x8*)(smem + rb + kb1);
        }
        #pragma unroll
        for (int nj = 0; nj < 2; ++nj) {
            const int rb = Bb + bRowByte + nj * 2048;
            b0[nj][0] = *(const bf16x8*)(smem + rb + kb0);
            b0[nj][1] = *(const bf16x8*)(smem + rb + kb1);
        }
        __builtin_amdgcn_s_barrier();
        asm volatile("s_waitcnt lgkmcnt(0)" ::: "memory");
        __builtin_amdgcn_sched_barrier(0);
        __builtin_amdgcn_s_setprio(1);
        #pragma unroll
        for (int mi = 0; mi < 4; ++mi)
            #pragma unroll
            for (int nj = 0; nj < 2; ++nj) {
                acc[mi][nj] = __builtin_amdgcn_mfma_f32_16x16x32_bf16(a[mi][0], b0[nj][0], acc[mi][nj], 0, 0, 0);
                acc[mi][nj] = __builtin_amdgcn_mfma_f32_16x16x32_bf16(a[mi][1], b0[nj][1], acc[mi][nj], 0, 0, 0);
            }
        __builtin_amdgcn_s_setprio(0);
        __builtin_amdgcn_s_barrier();

        // ---- phase 2: read b1 (B's last read) ----
        #pragma unroll
        for (int nj = 0; nj < 2; ++nj) {
            const int rb = Bb + bRowByte + 4096 + nj * 2048;
            b1[nj][0] = *(const bf16x8*)(smem + rb + kb0);
            b1[nj][1] = *(const bf16x8*)(smem + rb + kb1);
        }
        __builtin_amdgcn_s_barrier();
        asm volatile("s_waitcnt lgkmcnt(0)" ::: "memory");
        __builtin_amdgcn_sched_barrier(0);
        __builtin_amdgcn_s_setprio(1);
        #pragma unroll
        for (int mi = 0; mi < 4; ++mi)
            #pragma unroll
            for (int nj = 0; nj < 2; ++nj) {
                acc[mi][2 + nj] = __builtin_amdgcn_mfma_f32_16x16x32_bf16(a[mi][0], b1[nj][0], acc[mi][2 + nj], 0, 0, 0);
                acc[mi][2 + nj] = __builtin_amdgcn_mfma_f32_16x16x32_bf16(a[mi][1], b1[nj][1], acc[mi][2 + nj], 0, 0, 0);
            }
        __builtin_amdgcn_s_setprio(0);
        __builtin_amdgcn_s_barrier();

        // ---- phase 3: read a-hi (A's last read); stage (t+2).B0,B1 ----
        #pragma unroll
        for (int mi = 0; mi < 4; ++mi) {
            const int rb = Ab + aRowByte + 8192 + mi * 2048;
            a[mi][0] = *(const bf16x8*)(smem + rb + kb0);
            a[mi][1] = *(const bf16x8*)(smem + rb + kb1);
        }
        if (s2) { stage(B, ldb, n0,       (t + 2) << 6, Bb);
                  stage(B, ldb, n0 + 128, (t + 2) << 6, Bb + 16384); }
        __builtin_amdgcn_s_barrier();
        asm volatile("s_waitcnt lgkmcnt(0)" ::: "memory");
        __builtin_amdgcn_sched_barrier(0);
        __builtin_amdgcn_s_setprio(1);
        #pragma unroll
        for (int mi = 0; mi < 4; ++mi)
            #pragma unroll
            for (int nj = 0; nj < 2; ++nj) {
                acc[4 + mi][nj] = __builtin_amdgcn_mfma_f32_16x16x32_bf16(a[mi][0], b0[nj][0], acc[4 + mi][nj], 0, 0, 0);
                acc[4 + mi][nj] = __builtin_amdgcn_mfma_f32_16x16x32_bf16(a[mi][1], b0[nj][1], acc[4 + mi][nj], 0, 0, 0);
            }
        __builtin_amdgcn_s_setprio(0);
        __builtin_amdgcn_s_barrier();

        // ---- phase 4: stage (t+2).A0,A1; drain to 8 ----
        if (s2) { stage(A, lda, m0,       (t + 2) << 6, Ab);
                  stage(A, lda, m0 + 128, (t + 2) << 6, Ab + 16384); }
        __builtin_amdgcn_s_barrier();
        __builtin_amdgcn_s_setprio(1);
        #pragma unroll
        for (int mi = 0; mi < 4; ++mi)
            #pragma unroll
            for (int nj = 0; nj < 2; ++nj) {
                acc[4 + mi][2 + nj] = __builtin_amdgcn_mfma_f32_16x16x32_bf16(a[mi][0], b1[nj][0], acc[4 + mi][2 + nj], 0, 0, 0);
                acc[4 + mi][2 + nj] = __builtin_amdgcn_mfma_f32_16x16x32_bf16(a[mi][1], b1[nj][1], acc[4 + mi][2 + nj], 0, 0, 0);
            }
        __builtin_amdgcn_s_setprio(0);
        if (s2) { asm volatile("s_waitcnt vmcnt(8)" ::: "memory"); }
        else    { asm volatile("s_waitcnt vmcnt(0)" ::: "memory"); }
        __builtin_amdgcn_s_barrier();
    }

    // -------- epilogue --------
    u16* Cout; const float* bs; int ncol;
    if (n0 < ncut) { Cout = C1; bs = bias1; ncol = n0; }
    else           { Cout = C2; bs = bias2; ncol = n0 - ncut; }

    block_barrier();
    u16* lsu = (u16*)smem;
    const int lcolB = wn * 64 + fr;
    const int lrowB = wm * 128 + (lane >> 4) * 4;
    #pragma unroll
    for (int nj = 0; nj < 4; ++nj) {
        const int lcol = lcolB + nj * 16;
        const float bb = bs[ncol + lcol];
        #pragma unroll
        for (int mi = 0; mi < 8; ++mi) {
            #pragma unroll
            for (int j = 0; j < 4; ++j) {
                float v = acc[mi][nj][j] + bb;
                if constexpr (GELU) v = 0.5f * v * (1.f + erff(v * 0.70710678118f));
                lsu[(lrowB + mi * 16 + j) * 256 + lcol] = f2bf(v);
            }
        }
    }
    block_barrier();
    const int hp = tid & 31;
    const int r0 = tid >> 5;
    #pragma unroll
    for (int ps = 0; ps < 16; ++ps) {
        const int r = ps * 16 + r0;
        u16x8 v = *(const u16x8*)&lsu[r * 256 + hp * 8];
        *(u16x8*)&Cout[(size_t)(m0 + r) * ldc + ncol + hp * 8] = v;
    }
}

// ---------------------------------------------------------------------------
// 128x128 NT GEMM (m97 structure) — used for the attn1 PV GEMM.
// ---------------------------------------------------------------------------
template<int OUTF32, int HASBIAS>
__global__ __launch_bounds__(256, 2)
void gemm_nt(const u16* __restrict__ A, long sAg, int lda,
             const u16* __restrict__ B, long sBg, int ldb,
             void* __restrict__ Cv, long sCg, int ldc,
             const float* __restrict__ bias, int K, float scale)
{
    __shared__ __align__(16) u16 lsA[128 * 32];
    __shared__ __align__(16) u16 lsB[128 * 32];

    const int tid  = threadIdx.x;
    const int w    = tid >> 6;
    const int lane = tid & 63;
    const int m0   = blockIdx.x * 128;
    const int n0   = blockIdx.y * 128;
    A += (long)blockIdx.z * sAg;
    B += (long)blockIdx.z * sBg;

    const int wr = w >> 1, wc = w & 1;
    f32x4 acc[4][4] = {};

    const int srow = lane >> 2;
    const int skc  = (lane & 3) * 8;
    const int rA0  = 32 * w + srow;
    const int rA1  = rA0 + 16;
    const size_t aoff0 = (size_t)(m0 + rA0) * lda + skc;
    const size_t aoff1 = (size_t)(m0 + rA1) * lda + skc;
    const size_t boff0 = (size_t)(n0 + rA0) * ldb + skc;
    const size_t boff1 = (size_t)(n0 + rA1) * ldb + skc;
    u16* lA0 = lsA + 1024 * w;
    u16* lA1 = lA0 + 512;
    u16* lB0 = lsB + 1024 * w;
    u16* lB1 = lB0 + 512;

    const int fr = lane & 15;
    const int fk = (lane >> 4) * 8;

    for (int k0 = 0; k0 < K; k0 += 32) {
        gload_lds16(A + aoff0 + k0, lA0);
        gload_lds16(A + aoff1 + k0, lA1);
        gload_lds16(B + boff0 + k0, lB0);
        gload_lds16(B + boff1 + k0, lB1);
        __syncthreads();

        bf16x8 af[4], bf[4];
        #pragma unroll
        for (int m = 0; m < 4; m++)
            af[m] = *(const bf16x8*)&lsA[(wr * 64 + m * 16 + fr) * 32 + fk];
        #pragma unroll
        for (int n = 0; n < 4; n++)
            bf[n] = *(const bf16x8*)&lsB[(wc * 64 + n * 16 + fr) * 32 + fk];
        #pragma unroll
        for (int m = 0; m < 4; m++)
            #pragma unroll
            for (int n = 0; n < 4; n++)
                acc[m][n] = __builtin_amdgcn_mfma_f32_16x16x32_bf16(af[m], bf[n], acc[m][n], 0, 0, 0);
        __syncthreads();
    }

    float* Cf = (float*)Cv;
    u16*   Cb = (u16*)Cv;
    const int crow0 = m0 + wr * 64 + (lane >> 4) * 4;
    const int ccol0 = n0 + wc * 64 + fr;
    const long cbase = (long)blockIdx.z * sCg;
    #pragma unroll
    for (int n = 0; n < 4; n++) {
        const int col = ccol0 + n * 16;
        float bb = 0.f;
        if constexpr (HASBIAS) bb = bias[col];
        #pragma unroll
        for (int m = 0; m < 4; m++) {
            #pragma unroll
            for (int j = 0; j < 4; j++) {
                const int row = crow0 + m * 16 + j;
                float v = acc[m][n][j] + bb;
                const long idx = cbase + (long)row * ldc + col;
                if constexpr (OUTF32) Cf[idx] = v * scale;
                else                  Cb[idx] = f2bf(v);
            }
        }
    }
}

// ---------------------------------------------------------------------------
// attn1 scores + softmax fused: one block per (b,v) group.
// ---------------------------------------------------------------------------
__global__ __launch_bounds__(256, 1)
void scores_softmax_kernel(const u16* __restrict__ Q, const u16* __restrict__ KVp,
                           u16* __restrict__ P, float scale)
{
    __shared__ __align__(16) u16 lsA[128 * 32];
    __shared__ __align__(16) u16 lsB[128 * 32];
    __shared__ float SL[128][130];

    const int g = blockIdx.x;
    const u16* A = Q   + (size_t)g * 262144;
    const u16* B = KVp + (size_t)g * 262144;

    const int tid  = threadIdx.x;
    const int w    = tid >> 6;
    const int lane = tid & 63;
    const int wr = w >> 1, wc = w & 1;
    f32x4 acc[4][4] = {};

    const int srow = lane >> 2;
    const int skc  = (lane & 3) * 8;
    const int rA0  = 32 * w + srow;
    const int rA1  = rA0 + 16;
    const size_t aoff0 = (size_t)rA0 * 2048 + skc;
    const size_t aoff1 = (size_t)rA1 * 2048 + skc;
    u16* lA0 = lsA + 1024 * w;
    u16* lA1 = lA0 + 512;
    u16* lB0 = lsB + 1024 * w;
    u16* lB1 = lB0 + 512;

    const int fr = lane & 15;
    const int fk = (lane >> 4) * 8;

    for (int k0 = 0; k0 < 2048; k0 += 32) {
        gload_lds16(A + aoff0 + k0, lA0);
        gload_lds16(A + aoff1 + k0, lA1);
        gload_lds16(B + aoff0 + k0, lB0);
        gload_lds16(B + aoff1 + k0, lB1);
        __syncthreads();
        bf16x8 af[4], bf[4];
        #pragma unroll
        for (int m = 0; m < 4; m++)
            af[m] = *(const bf16x8*)&lsA[(wr * 64 + m * 16 + fr) * 32 + fk];
        #pragma unroll
        for (int n = 0; n < 4; n++)
            bf[n] = *(const bf16x8*)&lsB[(wc * 64 + n * 16 + fr) * 32 + fk];
        #pragma unroll
        for (int m = 0; m < 4; m++)
            #pragma unroll
            for (int n = 0; n < 4; n++)
                acc[m][n] = __builtin_amdgcn_mfma_f32_16x16x32_bf16(af[m], bf[n], acc[m][n], 0, 0, 0);
        __syncthreads();
    }

    const int crow0 = wr * 64 + (lane >> 4) * 4;
    const int ccol0 = wc * 64 + fr;
    #pragma unroll
    for (int n = 0; n < 4; n++)
        #pragma unroll
        for (int m = 0; m < 4; m++)
            #pragma unroll
            for (int j = 0; j < 4; j++)
                SL[crow0 + m * 16 + j][ccol0 + n * 16] = acc[m][n][j] * scale;
    __syncthreads();

    unsigned* Pout = (unsigned*)(P + (size_t)g * 16384);
    for (int r = w * 32; r < w * 32 + 32; ++r) {
        const float v0 = SL[r][lane * 2], v1 = SL[r][lane * 2 + 1];
        float mx = fmaxf(v0, v1);
        #pragma unroll
        for (int d = 1; d < 64; d <<= 1) mx = fmaxf(mx, __shfl_xor(mx, d));
        const float e0 = __expf(v0 - mx), e1 = __expf(v1 - mx);
        float sm = e0 + e1;
        #pragma unroll
        for (int d = 1; d < 64; d <<= 1) sm += __shfl_xor(sm, d);
        const float inv = 1.f / sm;
        Pout[r * 64 + lane] = (unsigned)f2bf(e0 * inv) | ((unsigned)f2bf(e1 * inv) << 16);
    }
}

// ---------------------------------------------------------------------------
__global__ __launch_bounds__(256)
void wtrans6_kernel(const float* w0, const float* w1, const float* w2,
                    const float* w3, const float* w4, const float* w5,
                    u16* o0, u16* o1, u16* o2, u16* o3, u16* o4, u16* o5)
{
    const float* ins[6]  = {w0, w1, w2, w3, w4, w5};
    u16*         outs[6] = {o0, o1, o2, o3, o4, o5};
    const float* in  = ins[blockIdx.z];
    u16*         out = outs[blockIdx.z];

    __shared__ float tile[32][33];
    const int c0 = blockIdx.x * 32, r0 = blockIdx.y * 32;
    const int tx = threadIdx.x & 31, ty = threadIdx.x >> 5;
    #pragma unroll
    for (int i = ty; i < 32; i += 8)
        tile[i][tx] = in[(size_t)(r0 + i) * 2048 + c0 + tx];
    __syncthreads();
    #pragma unroll
    for (int i = ty; i < 32; i += 8)
        out[(size_t)(c0 + i) * 2048 + r0 + tx] = f2bf(tile[tx][i]);
}

__global__ __launch_bounds__(256)
void wtrans_kernel(const float* __restrict__ in, u16* __restrict__ out, int R, int C)
{
    __shared__ float tile[32][33];
    const int c0 = blockIdx.x * 32, r0 = blockIdx.y * 32;
    const int tx = threadIdx.x & 31, ty = threadIdx.x >> 5;
    #pragma unroll
    for (int i = ty; i < 32; i += 8)
        tile[i][tx] = in[(size_t)(r0 + i) * C + c0 + tx];
    __syncthreads();
    #pragma unroll
    for (int i = ty; i < 32; i += 8)
        out[(size_t)(c0 + i) * R + r0 + tx] = f2bf(tile[tx][i]);
}

__global__ __launch_bounds__(256)
void kvtrans_kernel(const u16* __restrict__ in, u16* __restrict__ out)
{
    __shared__ u16 tile[32][33];
    const int g = blockIdx.z;
    const int n0 = blockIdx.x * 32, m0 = blockIdx.y * 32;
    const int tx = threadIdx.x & 31, ty = threadIdx.x >> 5;
    #pragma unroll
    for (int i = ty; i < 32; i += 8)
        tile[i][tx] = in[(size_t)(g * 128 + m0 + i) * 2048 + n0 + tx];
    __syncthreads();
    #pragma unroll
    for (int i = ty; i < 32; i += 8)
        out[(size_t)g * 262144 + (size_t)(n0 + i) * 128 + m0 + tx] = tile[tx][i];
}

__global__ __launch_bounds__(256)
void cvt_f32_bf16(const float* __restrict__ in, u16* __restrict__ out)
{
    const long i = ((long)blockIdx.x * 256 + threadIdx.x) * 4;
    float4 v = *(const float4*)(in + i);
    u16x4 o;
    o[0] = f2bf(v.x); o[1] = f2bf(v.y); o[2] = f2bf(v.z); o[3] = f2bf(v.w);
    *(u16x4*)(out + i) = o;
}

// ---------------------------------------------------------------------------
// LayerNorm.  RESF32: resid is f32 (first LN) else bf16.
// FINAL=0: write xb = bf16(LN output); residual chain lives in xb (post-LN).
// FINAL=1: write o1,o2 (f32 d_out x2).
// ---------------------------------------------------------------------------
template<int FINAL, int RESF32>
__global__ __launch_bounds__(256)
void ln_kernel(const void* __restrict__ residv, const u16* __restrict__ add,
               const float* __restrict__ gam, const float* __restrict__ bet,
               u16* __restrict__ xb, float* __restrict__ o1, float* __restrict__ o2)
{
    const long row = blockIdx.x;
    const int  t   = threadIdx.x;
    const long base = row * PD + t * 8;

    u16x8 av = *(const u16x8*)(add + base);
    float y[8];
    if constexpr (RESF32) {
        const float* resid = (const float*)residv;
        float4 r0 = *(const float4*)(resid + base);
        float4 r1 = *(const float4*)(resid + base + 4);
        y[0] = r0.x + bf2f(av[0]); y[1] = r0.y + bf2f(av[1]);
        y[2] = r0.z + bf2f(av[2]); y[3] = r0.w + bf2f(av[3]);
        y[4] = r1.x + bf2f(av[4]); y[5] = r1.y + bf2f(av[5]);
        y[6] = r1.z + bf2f(av[6]); y[7] = r1.w + bf2f(av[7]);
    } else {
        const u16* resid = (const u16*)residv;
        u16x8 rv = *(const u16x8*)(resid + base);
        #pragma unroll
        for (int j = 0; j < 8; j++) y[j] = bf2f(rv[j]) + bf2f(av[j]);
    }

    float s1 = 0.f, s2 = 0.f;
    #pragma unroll
    for (int j = 0; j < 8; j++) { s1 += y[j]; s2 += y[j] * y[j]; }
    #pragma unroll
    for (int d = 1; d < 64; d <<= 1) { s1 += __shfl_xor(s1, d); s2 += __shfl_xor(s2, d); }
    __shared__ float red[8];
    const int w = t >> 6;
    if ((t & 63) == 0) { red[w] = s1; red[4 + w] = s2; }
    __syncthreads();
    s1 = red[0] + red[1] + red[2] + red[3];
    s2 = red[4] + red[5] + red[6] + red[7];
    const float mean = s1 * (1.f / PD);
    const float var  = s2 * (1.f / PD) - mean * mean;
    const float rstd = rsqrtf(var + 1e-5f);

    float4 g0 = *(const float4*)(gam + t * 8);
    float4 g1 = *(const float4*)(gam + t * 8 + 4);
    float4 b0 = *(const float4*)(bet + t * 8);
    float4 b1 = *(const float4*)(bet + t * 8 + 4);
    float gv[8] = {g0.x, g0.y, g0.z, g0.w, g1.x, g1.y, g1.z, g1.w};
    float bv[8] = {b0.x, b0.y, b0.z, b0.w, b1.x, b1.y, b1.z, b1.w};

    float o[8];
    #pragma unroll
    for (int j = 0; j < 8; j++) o[j] = (y[j] - mean) * rstd * gv[j] + bv[j];

    if constexpr (FINAL) {
        float4 p0 = {o[0], o[1], o[2], o[3]}, p1 = {o[4], o[5], o[6], o[7]};
        *(float4*)(o1 + base) = p0; *(float4*)(o1 + base + 4) = p1;
        *(float4*)(o2 + base) = p0; *(float4*)(o2 + base + 4) = p1;
    } else {
        u16x8 ob;
        #pragma unroll
        for (int j = 0; j < 8; j++) ob[j] = f2bf(o[j]);
        *(u16x8*)(xb + base) = ob;
    }
}

__global__ void detect_mask_kernel(const unsigned char* __restrict__ m, int* __restrict__ flag)
{
    __shared__ int s;
    if (threadIdx.x == 0) s = 0;
    __syncthreads();
    int acc = 0;
    for (int i = threadIdx.x; i < 2048; i += 256)
        if (i & 3) acc |= m[i];
    if (acc) atomicOr(&s, 1);
    __syncthreads();
    if (threadIdx.x == 0) *flag = s;
}

// ---------------------------------------------------------------------------
// attn2: per (b,p) group over V=16.  2 waves: wave0 = MFMA scores + masked
// softmax; both waves = PV at n-stride 128.
// ---------------------------------------------------------------------------
__global__ __launch_bounds__(128)
void attn2_kernel(u16* __restrict__ Q, const u16* __restrict__ KV,
                  const void* __restrict__ mask, const int* __restrict__ mflag,
                  float scale)
{
    const int g = blockIdx.x;
    const int b = g >> 7, p = g & 127;
    const int tid  = threadIdx.x;
    const int lane = tid & 63;
    const int w    = tid >> 6;

    const size_t groupbase = ((size_t)(b * 16) * 128 + p) * PD;
    const size_t vstride   = (size_t)128 * PD;

    __shared__ float PL[16][16];

    if (w == 0) {
        const int am   = lane & 15;
        const int koff = (lane >> 4) * 8;
        const u16* qp = Q  + groupbase + (size_t)am * vstride + koff;
        const u16* kp = KV + groupbase + (size_t)am * vstride + koff;

        f32x4 acc = {0.f, 0.f, 0.f, 0.f};
        for (int k0 = 0; k0 < PD; k0 += 32) {
            bf16x8 a  = *(const bf16x8*)(qp + k0);
            bf16x8 bb = *(const bf16x8*)(kp + k0);
            acc = __builtin_amdgcn_mfma_f32_16x16x32_bf16(a, bb, acc, 0, 0, 0);
        }

        const int vk = lane & 15;
        const int hi = lane >> 4;
        const int mf = *mflag;
        float pv[4];
        #pragma unroll
        for (int j = 0; j < 4; j++) {
            const int vq = hi * 4 + j;
            float s = acc[j] * scale;
            const int midx = b * 256 + vq * 16 + vk;
            int msk;
            if (mf) msk = ((const unsigned char*)mask)[midx];
            else    msk = ((const int*)mask)[midx];
            if (msk) s = -1e30f;
            pv[j] = s;
        }
        #pragma unroll
        for (int j = 0; j < 4; j++) {
            float mx = pv[j];
            #pragma unroll
            for (int d = 1; d < 16; d <<= 1) mx = fmaxf(mx, __shfl_xor(mx, d));
            const float e = __expf(pv[j] - mx);
            float sm = e;
            #pragma unroll
            for (int d = 1; d < 16; d <<= 1) sm += __shfl_xor(sm, d);
            pv[j] = e / sm;
        }
        #pragma unroll
        for (int j = 0; j < 4; j++) PL[hi * 4 + j][vk] = pv[j];
    }
    __syncthreads();

    const u16* kvr[16];
    #pragma unroll
    for (int v = 0; v < 16; v++) kvr[v] = KV + groupbase + (size_t)v * vstride;

    for (int vqt = 0; vqt < 16; vqt += 4) {
        float pr[4][16];
        #pragma unroll
        for (int q = 0; q < 4; q++)
            #pragma unroll
            for (int k = 0; k < 16; k++) pr[q][k] = PL[vqt + q][k];
        u16* o0 = Q + groupbase + (size_t)(vqt + 0) * vstride;
        u16* o1 = Q + groupbase + (size_t)(vqt + 1) * vstride;
        u16* o2 = Q + groupbase + (size_t)(vqt + 2) * vstride;
        u16* o3 = Q + groupbase + (size_t)(vqt + 3) * vstride;
        for (int n0 = 0; n0 < PD; n0 += 128) {
            const int n = n0 + tid;
            float a0 = 0.f, a1 = 0.f, a2 = 0.f, a3 = 0.f;
            #pragma unroll
            for (int k = 0; k < 16; k++) {
                const float kvv = bf2f(kvr[k][n]);
                a0 += pr[0][k] * kvv; a1 += pr[1][k] * kvv;
                a2 += pr[2][k] * kvv; a3 += pr[3][k] * kvv;
            }
            o0[n] = f2bf(a0); o1[n] = f2bf(a1); o2[n] = f2bf(a2); o3[n] = f2bf(a3);
        }
    }
}

// ---------------------------------------------------------------------------
extern "C" void kernel_launch(void* const* d_in, const int* in_sizes, int n_in,
                              void* d_out, int out_size, void* d_ws, size_t ws_size,
                              hipStream_t stream)
{
    const float* x0    = (const float*)d_in[0];
    const void*  vmask = d_in[1];
    const float* w_q1  = (const float*)d_in[2];  const float* b_q1  = (const float*)d_in[3];
    const float* w_kv1 = (const float*)d_in[4];  const float* b_kv1 = (const float*)d_in[5];
    const float* w_o1  = (const float*)d_in[6];  const float* b_o1  = (const float*)d_in[7];
    const float* w_q2  = (const float*)d_in[8];  const float* b_q2  = (const float*)d_in[9];
    const float* w_kv2 = (const float*)d_in[10]; const float* b_kv2 = (const float*)d_in[11];
    const float* w_o2  = (const float*)d_in[12]; const float* b_o2  = (const float*)d_in[13];
    const float* g1 = (const float*)d_in[14]; const float* be1 = (const float*)d_in[15];
    const float* g2 = (const float*)d_in[16]; const float* be2 = (const float*)d_in[17];
    const float* g3 = (const float*)d_in[18]; const float* be3 = (const float*)d_in[19];
    const float* w_l1 = (const float*)d_in[20]; const float* b_l1 = (const float*)d_in[21];
    const float* w_l2 = (const float*)d_in[22]; const float* b_l2 = (const float*)d_in[23];

    char* ws = (char*)d_ws;
    size_t off = 0;
    auto alloc = [&](size_t bytes) { size_t o = off; off += (bytes + 255) & ~(size_t)255; return o; };
    const size_t oWQ1  = alloc(8388608),  oWKV1 = alloc(8388608),  oWO1 = alloc(8388608);
    const size_t oWQ2  = alloc(8388608),  oWKV2 = alloc(8388608),  oWO2 = alloc(8388608);
    const size_t oWL1  = alloc(33554432), oWL2  = alloc(33554432);
    const size_t oXB   = alloc(67108864);
    const size_t oQ    = alloc(67108864);   // Q and KV contiguous: FFN hidden reuses both
    const size_t oKV   = alloc(67108864);
    const size_t oKVT  = alloc(67108864);
    const size_t oP1   = alloc(4194304);
    const size_t oFLAG = alloc(256);
    if (ws_size < off) return;

    u16* WQ1T = (u16*)(ws + oWQ1);  u16* WKV1T = (u16*)(ws + oWKV1); u16* WO1T = (u16*)(ws + oWO1);
    u16* WQ2T = (u16*)(ws + oWQ2);  u16* WKV2T = (u16*)(ws + oWKV2); u16* WO2T = (u16*)(ws + oWO2);
    u16* WL1T = (u16*)(ws + oWL1);  u16* WL2T  = (u16*)(ws + oWL2);
    u16* XB   = (u16*)(ws + oXB);   u16* Q     = (u16*)(ws + oQ);
    u16* KV   = (u16*)(ws + oKV);   u16* KVT   = (u16*)(ws + oKVT);
    u16* P1   = (u16*)(ws + oP1);   int* FLAG  = (int*)(ws + oFLAG);
    u16* H    = Q;                  // 128 MB hidden buffer (Q+KV regions)
    u16* F    = KVT;                // FFN output buffer

    const float scale = 0.02209708691f;  // 1/sqrt(2048)
    float* out0 = (float*)d_out;
    float* out1 = out0 + (size_t)NROWS * PD;

    detect_mask_kernel<<<1, 256, 0, stream>>>((const unsigned char*)vmask, FLAG);

    wtrans6_kernel<<<dim3(64, 64, 6), 256, 0, stream>>>(w_q1, w_kv1, w_o1, w_q2, w_kv2, w_o2,
                                                        WQ1T, WKV1T, WO1T, WQ2T, WKV2T, WO2T);
    wtrans_kernel<<<dim3(256, 64), 256, 0, stream>>>(w_l1, WL1T, 2048, 8192);
    wtrans_kernel<<<dim3(64, 256), 256, 0, stream>>>(w_l2, WL2T, 8192, 2048);

    cvt_f32_bf16<<<32768, 256, 0, stream>>>(x0, XB);

    const int BIG = 1 << 30;

    // ---- attn1 ----
    gemm256<0><<<1024, 512, 0, stream>>>(XB, 2048, WQ1T, 2048, Q, KV, 2048, 2048,
                                         b_q1, b_kv1, 2048, 16, 32, 4);
    kvtrans_kernel<<<dim3(64, 4, 128), 256, 0, stream>>>(KV, KVT);
    scores_softmax_kernel<<<128, 256, 0, stream>>>(Q, KV, P1, scale);
    gemm_nt<0,0><<<dim3(1,16,128), 256, 0, stream>>>(P1, 16384, 128, KVT, 262144, 128, Q, 262144, 2048, nullptr, 128, 1.f);
    gemm256<0><<<512, 512, 0, stream>>>(Q, 2048, WO1T, 2048, KV, KV, BIG, 2048,
                                        b_o1, b_o1, 2048, 8, 32, 2);
    ln_kernel<0,1><<<NROWS, 256, 0, stream>>>(x0, KV, g1, be1, XB, nullptr, nullptr);

    // ---- attn2 ----
    gemm256<0><<<1024, 512, 0, stream>>>(XB, 2048, WQ2T, 2048, Q, KV, 2048, 2048,
                                         b_q2, b_kv2, 2048, 16, 32, 4);
    attn2_kernel<<<1024, 128, 0, stream>>>(Q, KV, vmask, FLAG, scale);
    gemm256<0><<<512, 512, 0, stream>>>(Q, 2048, WO2T, 2048, KV, KV, BIG, 2048,
                                        b_o2, b_o2, 2048, 8, 32, 2);
    ln_kernel<0,0><<<NROWS, 256, 0, stream>>>(XB, KV, g2, be2, XB, nullptr, nullptr);

    // ---- FFN: 2 row-chunks of 8192, l1(c) then l2(c) for L3-warm H ----
    for (int c = 0; c < 2; c++) {
        const size_t rows = (size_t)c * 8192;
        gemm256<1><<<1024, 512, 0, stream>>>(XB + rows * 2048, 2048, WL1T, 2048,
                                             H, H, BIG, 8192, b_l1, b_l1, 2048, 32, 32, 4);
        gemm256<0><<<256, 512, 0, stream>>>(H, 8192, WL2T, 8192,
                                            F + rows * 2048, F + rows * 2048, BIG, 2048,
                                            b_l2, b_l2, 8192, 8, 32, 1);
    }
    ln_kernel<1,0><<<NROWS, 256, 0, stream>>>(XB, F, g3, be3, nullptr, out0, out1);
}

// Round 16
// 2372.127 us; speedup vs baseline: 1.0295x; 1.0295x over previous
//
#include <hip/hip_runtime.h>
#include <math.h>

// ---------------------------------------------------------------------------
// Encoder_Cross: B=8,V=16,P=128,L=16,D=128, PD=2048.  FINAL (R14 config).
// gemm256: R6/R10-proven 4-phase schedule (best measured config, ~658 TF).
// Glue: fused QKV, fused scores+softmax, residual chain through XB,
// attn2 = 2 waves (wave0 scores+softmax; both waves PV @stride128).
// ---------------------------------------------------------------------------

using u16   = unsigned short;
using f32x4 = __attribute__((ext_vector_type(4))) float;
using bf16x8= __attribute__((ext_vector_type(8))) __bf16;
using u16x8 = __attribute__((ext_vector_type(8))) u16;
using u16x4 = __attribute__((ext_vector_type(4))) u16;

#define NROWS 16384   // B*V*P
#define PD    2048
#define MEMBAR asm volatile("" ::: "memory")

__device__ __forceinline__ float bf2f(u16 u) {
    unsigned v = ((unsigned)u) << 16;
    return __builtin_bit_cast(float, v);
}
__device__ __forceinline__ u16 f2bf(float f) {
    unsigned u = __builtin_bit_cast(unsigned, f);
    u += 0x7FFFu + ((u >> 16) & 1u);        // RNE
    return (u16)(u >> 16);
}
__device__ __forceinline__ void gload_lds16(const void* g, void* l) {
    __builtin_amdgcn_global_load_lds((const __attribute__((address_space(1))) void*)g,
                                     (__attribute__((address_space(3))) void*)l, 16, 0, 0);
}
__device__ __forceinline__ void block_barrier() {
    MEMBAR; __builtin_amdgcn_s_barrier(); MEMBAR;
}

// ---------------------------------------------------------------------------
// 256x256-tile NT GEMM (R6 schedule):  C[m][n] = sum_k A[m][k]*B[n][k] + bias
// 4 phases/K-tile: P1 {read a-lo,b0; stage t+1.B1} P2 {read b1; stage t+1.A1}
// P3 {read a-hi; stage t+2.B0} P4 {stage t+2.A0; vmcnt(4)}.  Region-lifetime
// invariant: same-buffer regions staged only after their last-read phase's
// closing barrier.  Do not merge phases (R7/R11 broke this twice).
// ---------------------------------------------------------------------------
template<int GELU>
__global__ __launch_bounds__(512, 2)
void gemm256(const u16* __restrict__ A, int lda,
             const u16* __restrict__ B, int ldb,
             u16* __restrict__ C1, u16* __restrict__ C2, int ncut, int ldc,
             const float* __restrict__ bias1, const float* __restrict__ bias2,
             int K, int NT, int CM, int CN)
{
    __shared__ __align__(16) char smem[131072];

    const int tid  = threadIdx.x;
    const int wv   = tid >> 6;
    const int wm   = wv >> 2;          // 0..1
    const int wn   = wv & 3;           // 0..3
    const int lane = tid & 63;
    const int fr   = lane & 15;
    const int fks16= (lane >> 4) * 16;
    const int rmask= (fr & 7) << 4;
    const int kb0  = fks16 ^ rmask;
    const int kb1  = (64 + fks16) ^ rmask;

    const int xcd = blockIdx.x & 7;
    const int ii  = blockIdx.x >> 3;
    const int RY  = NT / CN;
    const int mt  = (xcd / RY) * CM + (ii / CN);
    const int nt  = (xcd % RY) * CN + (ii % CN);
    const int m0  = mt * 256;
    const int n0  = nt * 256;

    const int rsub = tid >> 3;
    const int cswE = (((tid & 7) * 16) ^ ((rsub & 7) << 4)) >> 1;
    const int waveByte = wv * 1024;

    auto stage = [&](const u16* mat, int ld, int row0, int k0, int regionByte) {
        const u16* g0 = mat + (size_t)(row0 + rsub) * ld + k0 + cswE;
        gload_lds16(g0,                   smem + regionByte + waveByte);
        gload_lds16(g0 + (size_t)ld * 64, smem + regionByte + 8192 + waveByte);
    };

    const int aRowByte = (wm * 128 + fr) * 128;
    const int bRowByte = (wn * 64 + fr) * 128;

    const int KT = K >> 6;

    stage(A, lda, m0,       0, 0);          // t0.A0
    stage(B, ldb, n0,       0, 32768);      // t0.B0
    stage(A, lda, m0 + 128, 0, 16384);      // t0.A1
    stage(B, ldb, n0 + 128, 0, 49152);      // t0.B1
    stage(B, ldb, n0,      64, 98304);      // t1.B0
    stage(A, lda, m0,      64, 65536);      // t1.A0
    asm volatile("s_waitcnt vmcnt(4)" ::: "memory");
    __builtin_amdgcn_s_barrier();

    bf16x8 a[4][2], b0[2][2], b1[2][2];
    f32x4  acc[8][4] = {};

    for (int t = 0; t < KT; ++t) {
        const int Ab = (t & 1) ? 65536 : 0;
        const int Bb = Ab + 32768;
        const int Ob = Ab ^ 65536;
        const bool s1 = (t + 1 < KT), s2 = (t + 2 < KT);

        // ---- phase 1 ----
        #pragma unroll
        for (int mi = 0; mi < 4; ++mi) {
            const int rb = Ab + aRowByte + mi * 2048;
            a[mi][0] = *(const bf16x8*)(smem + rb + kb0);
            a[mi][1] = *(const bf16x8*)(smem + rb + kb1);
        }
        #pragma unroll
        for (int nj = 0; nj < 2; ++nj) {
            const int rb = Bb + bRowByte + nj * 2048;
            b0[nj][0] = *(const bf16x8*)(smem + rb + kb0);
            b0[nj][1] = *(const bf16x8*)(smem + rb + kb1);
        }
        if (s1) stage(B, ldb, n0 + 128, (t + 1) << 6, Ob + 49152);
        __builtin_amdgcn_s_barrier();
        asm volatile("s_waitcnt lgkmcnt(0)" ::: "memory");
        __builtin_amdgcn_sched_barrier(0);
        __builtin_amdgcn_s_setprio(1);
        #pragma unroll
        for (int mi = 0; mi < 4; ++mi)
            #pragma unroll
            for (int nj = 0; nj < 2; ++nj) {
                acc[mi][nj] = __builtin_amdgcn_mfma_f32_16x16x32_bf16(a[mi][0], b0[nj][0], acc[mi][nj], 0, 0, 0);
                acc[mi][nj] = __builtin_amdgcn_mfma_f32_16x16x32_bf16(a[mi][1], b0[nj][1], acc[mi][nj], 0, 0, 0);
            }
        __builtin_amdgcn_s_setprio(0);
        __builtin_amdgcn_s_barrier();

        // ---- phase 2 ----
        #pragma unroll
        for (int nj = 0; nj < 2; ++nj) {
            const int rb = Bb + bRowByte + 4096 + nj * 2048;
            b1[nj][0] = *(const bf16x8*)(smem + rb + kb0);
            b1[nj][1] = *(const bf16x8*)(smem + rb + kb1);
        }
        if (s1) stage(A, lda, m0 + 128, (t + 1) << 6, Ob + 16384);
        __builtin_amdgcn_s_barrier();
        asm volatile("s_waitcnt lgkmcnt(0)" ::: "memory");
        __builtin_amdgcn_sched_barrier(0);
        __builtin_amdgcn_s_setprio(1);
        #pragma unroll
        for (int mi = 0; mi < 4; ++mi)
            #pragma unroll
            for (int nj = 0; nj < 2; ++nj) {
                acc[mi][2 + nj] = __builtin_amdgcn_mfma_f32_16x16x32_bf16(a[mi][0], b1[nj][0], acc[mi][2 + nj], 0, 0, 0);
                acc[mi][2 + nj] = __builtin_amdgcn_mfma_f32_16x16x32_bf16(a[mi][1], b1[nj][1], acc[mi][2 + nj], 0, 0, 0);
            }
        __builtin_amdgcn_s_setprio(0);
        __builtin_amdgcn_s_barrier();

        // ---- phase 3 ----
        #pragma unroll
        for (int mi = 0; mi < 4; ++mi) {
            const int rb = Ab + aRowByte + 8192 + mi * 2048;
            a[mi][0] = *(const bf16x8*)(smem + rb + kb0);
            a[mi][1] = *(const bf16x8*)(smem + rb + kb1);
        }
        if (s2) stage(B, ldb, n0, (t + 2) << 6, Bb);
        __builtin_amdgcn_s_barrier();
        asm volatile("s_waitcnt lgkmcnt(0)" ::: "memory");
        __builtin_amdgcn_sched_barrier(0);
        __builtin_amdgcn_s_setprio(1);
        #pragma unroll
        for (int mi = 0; mi < 4; ++mi)
            #pragma unroll
            for (int nj = 0; nj < 2; ++nj) {
                acc[4 + mi][nj] = __builtin_amdgcn_mfma_f32_16x16x32_bf16(a[mi][0], b0[nj][0], acc[4 + mi][nj], 0, 0, 0);
                acc[4 + mi][nj] = __builtin_amdgcn_mfma_f32_16x16x32_bf16(a[mi][1], b0[nj][1], acc[4 + mi][nj], 0, 0, 0);
            }
        __builtin_amdgcn_s_setprio(0);
        __builtin_amdgcn_s_barrier();

        // ---- phase 4 ----
        if (s2) stage(A, lda, m0, (t + 2) << 6, Ab);
        __builtin_amdgcn_s_barrier();
        __builtin_amdgcn_s_setprio(1);
        #pragma unroll
        for (int mi = 0; mi < 4; ++mi)
            #pragma unroll
            for (int nj = 0; nj < 2; ++nj) {
                acc[4 + mi][2 + nj] = __builtin_amdgcn_mfma_f32_16x16x32_bf16(a[mi][0], b1[nj][0], acc[4 + mi][2 + nj], 0, 0, 0);
                acc[4 + mi][2 + nj] = __builtin_amdgcn_mfma_f32_16x16x32_bf16(a[mi][1], b1[nj][1], acc[4 + mi][2 + nj], 0, 0, 0);
            }
        __builtin_amdgcn_s_setprio(0);
        if (s2) { asm volatile("s_waitcnt vmcnt(4)" ::: "memory"); }
        else    { asm volatile("s_waitcnt vmcnt(0)" ::: "memory"); }
        __builtin_amdgcn_s_barrier();
    }

    // -------- epilogue --------
    u16* Cout; const float* bs; int ncol;
    if (n0 < ncut) { Cout = C1; bs = bias1; ncol = n0; }
    else           { Cout = C2; bs = bias2; ncol = n0 - ncut; }

    block_barrier();
    u16* lsu = (u16*)smem;
    const int lcolB = wn * 64 + fr;
    const int lrowB = wm * 128 + (lane >> 4) * 4;
    #pragma unroll
    for (int nj = 0; nj < 4; ++nj) {
        const int lcol = lcolB + nj * 16;
        const float bb = bs[ncol + lcol];
        #pragma unroll
        for (int mi = 0; mi < 8; ++mi) {
            #pragma unroll
            for (int j = 0; j < 4; ++j) {
                float v = acc[mi][nj][j] + bb;
                if constexpr (GELU) v = 0.5f * v * (1.f + erff(v * 0.70710678118f));
                lsu[(lrowB + mi * 16 + j) * 256 + lcol] = f2bf(v);
            }
        }
    }
    block_barrier();
    const int hp = tid & 31;
    const int r0 = tid >> 5;
    #pragma unroll
    for (int ps = 0; ps < 16; ++ps) {
        const int r = ps * 16 + r0;
        u16x8 v = *(const u16x8*)&lsu[r * 256 + hp * 8];
        *(u16x8*)&Cout[(size_t)(m0 + r) * ldc + ncol + hp * 8] = v;
    }
}

// ---------------------------------------------------------------------------
// 128x128 NT GEMM (m97 structure) — used for the attn1 PV GEMM.
// ---------------------------------------------------------------------------
template<int OUTF32, int HASBIAS>
__global__ __launch_bounds__(256, 2)
void gemm_nt(const u16* __restrict__ A, long sAg, int lda,
             const u16* __restrict__ B, long sBg, int ldb,
             void* __restrict__ Cv, long sCg, int ldc,
             const float* __restrict__ bias, int K, float scale)
{
    __shared__ __align__(16) u16 lsA[128 * 32];
    __shared__ __align__(16) u16 lsB[128 * 32];

    const int tid  = threadIdx.x;
    const int w    = tid >> 6;
    const int lane = tid & 63;
    const int m0   = blockIdx.x * 128;
    const int n0   = blockIdx.y * 128;
    A += (long)blockIdx.z * sAg;
    B += (long)blockIdx.z * sBg;

    const int wr = w >> 1, wc = w & 1;
    f32x4 acc[4][4] = {};

    const int srow = lane >> 2;
    const int skc  = (lane & 3) * 8;
    const int rA0  = 32 * w + srow;
    const int rA1  = rA0 + 16;
    const size_t aoff0 = (size_t)(m0 + rA0) * lda + skc;
    const size_t aoff1 = (size_t)(m0 + rA1) * lda + skc;
    const size_t boff0 = (size_t)(n0 + rA0) * ldb + skc;
    const size_t boff1 = (size_t)(n0 + rA1) * ldb + skc;
    u16* lA0 = lsA + 1024 * w;
    u16* lA1 = lA0 + 512;
    u16* lB0 = lsB + 1024 * w;
    u16* lB1 = lB0 + 512;

    const int fr = lane & 15;
    const int fk = (lane >> 4) * 8;

    for (int k0 = 0; k0 < K; k0 += 32) {
        gload_lds16(A + aoff0 + k0, lA0);
        gload_lds16(A + aoff1 + k0, lA1);
        gload_lds16(B + boff0 + k0, lB0);
        gload_lds16(B + boff1 + k0, lB1);
        __syncthreads();

        bf16x8 af[4], bf[4];
        #pragma unroll
        for (int m = 0; m < 4; m++)
            af[m] = *(const bf16x8*)&lsA[(wr * 64 + m * 16 + fr) * 32 + fk];
        #pragma unroll
        for (int n = 0; n < 4; n++)
            bf[n] = *(const bf16x8*)&lsB[(wc * 64 + n * 16 + fr) * 32 + fk];
        #pragma unroll
        for (int m = 0; m < 4; m++)
            #pragma unroll
            for (int n = 0; n < 4; n++)
                acc[m][n] = __builtin_amdgcn_mfma_f32_16x16x32_bf16(af[m], bf[n], acc[m][n], 0, 0, 0);
        __syncthreads();
    }

    float* Cf = (float*)Cv;
    u16*   Cb = (u16*)Cv;
    const int crow0 = m0 + wr * 64 + (lane >> 4) * 4;
    const int ccol0 = n0 + wc * 64 + fr;
    const long cbase = (long)blockIdx.z * sCg;
    #pragma unroll
    for (int n = 0; n < 4; n++) {
        const int col = ccol0 + n * 16;
        float bb = 0.f;
        if constexpr (HASBIAS) bb = bias[col];
        #pragma unroll
        for (int m = 0; m < 4; m++) {
            #pragma unroll
            for (int j = 0; j < 4; j++) {
                const int row = crow0 + m * 16 + j;
                float v = acc[m][n][j] + bb;
                const long idx = cbase + (long)row * ldc + col;
                if constexpr (OUTF32) Cf[idx] = v * scale;
                else                  Cb[idx] = f2bf(v);
            }
        }
    }
}

// ---------------------------------------------------------------------------
// attn1 scores + softmax fused: one block per (b,v) group.
// ---------------------------------------------------------------------------
__global__ __launch_bounds__(256, 1)
void scores_softmax_kernel(const u16* __restrict__ Q, const u16* __restrict__ KVp,
                           u16* __restrict__ P, float scale)
{
    __shared__ __align__(16) u16 lsA[128 * 32];
    __shared__ __align__(16) u16 lsB[128 * 32];
    __shared__ float SL[128][130];

    const int g = blockIdx.x;
    const u16* A = Q   + (size_t)g * 262144;
    const u16* B = KVp + (size_t)g * 262144;

    const int tid  = threadIdx.x;
    const int w    = tid >> 6;
    const int lane = tid & 63;
    const int wr = w >> 1, wc = w & 1;
    f32x4 acc[4][4] = {};

    const int srow = lane >> 2;
    const int skc  = (lane & 3) * 8;
    const int rA0  = 32 * w + srow;
    const int rA1  = rA0 + 16;
    const size_t aoff0 = (size_t)rA0 * 2048 + skc;
    const size_t aoff1 = (size_t)rA1 * 2048 + skc;
    u16* lA0 = lsA + 1024 * w;
    u16* lA1 = lA0 + 512;
    u16* lB0 = lsB + 1024 * w;
    u16* lB1 = lB0 + 512;

    const int fr = lane & 15;
    const int fk = (lane >> 4) * 8;

    for (int k0 = 0; k0 < 2048; k0 += 32) {
        gload_lds16(A + aoff0 + k0, lA0);
        gload_lds16(A + aoff1 + k0, lA1);
        gload_lds16(B + aoff0 + k0, lB0);
        gload_lds16(B + aoff1 + k0, lB1);
        __syncthreads();
        bf16x8 af[4], bf[4];
        #pragma unroll
        for (int m = 0; m < 4; m++)
            af[m] = *(const bf16x8*)&lsA[(wr * 64 + m * 16 + fr) * 32 + fk];
        #pragma unroll
        for (int n = 0; n < 4; n++)
            bf[n] = *(const bf16x8*)&lsB[(wc * 64 + n * 16 + fr) * 32 + fk];
        #pragma unroll
        for (int m = 0; m < 4; m++)
            #pragma unroll
            for (int n = 0; n < 4; n++)
                acc[m][n] = __builtin_amdgcn_mfma_f32_16x16x32_bf16(af[m], bf[n], acc[m][n], 0, 0, 0);
        __syncthreads();
    }

    const int crow0 = wr * 64 + (lane >> 4) * 4;
    const int ccol0 = wc * 64 + fr;
    #pragma unroll
    for (int n = 0; n < 4; n++)
        #pragma unroll
        for (int m = 0; m < 4; m++)
            #pragma unroll
            for (int j = 0; j < 4; j++)
                SL[crow0 + m * 16 + j][ccol0 + n * 16] = acc[m][n][j] * scale;
    __syncthreads();

    unsigned* Pout = (unsigned*)(P + (size_t)g * 16384);
    for (int r = w * 32; r < w * 32 + 32; ++r) {
        const float v0 = SL[r][lane * 2], v1 = SL[r][lane * 2 + 1];
        float mx = fmaxf(v0, v1);
        #pragma unroll
        for (int d = 1; d < 64; d <<= 1) mx = fmaxf(mx, __shfl_xor(mx, d));
        const float e0 = __expf(v0 - mx), e1 = __expf(v1 - mx);
        float sm = e0 + e1;
        #pragma unroll
        for (int d = 1; d < 64; d <<= 1) sm += __shfl_xor(sm, d);
        const float inv = 1.f / sm;
        Pout[r * 64 + lane] = (unsigned)f2bf(e0 * inv) | ((unsigned)f2bf(e1 * inv) << 16);
    }
}

// ---------------------------------------------------------------------------
__global__ __launch_bounds__(256)
void wtrans6_kernel(const float* w0, const float* w1, const float* w2,
                    const float* w3, const float* w4, const float* w5,
                    u16* o0, u16* o1, u16* o2, u16* o3, u16* o4, u16* o5)
{
    const float* ins[6]  = {w0, w1, w2, w3, w4, w5};
    u16*         outs[6] = {o0, o1, o2, o3, o4, o5};
    const float* in  = ins[blockIdx.z];
    u16*         out = outs[blockIdx.z];

    __shared__ float tile[32][33];
    const int c0 = blockIdx.x * 32, r0 = blockIdx.y * 32;
    const int tx = threadIdx.x & 31, ty = threadIdx.x >> 5;
    #pragma unroll
    for (int i = ty; i < 32; i += 8)
        tile[i][tx] = in[(size_t)(r0 + i) * 2048 + c0 + tx];
    __syncthreads();
    #pragma unroll
    for (int i = ty; i < 32; i += 8)
        out[(size_t)(c0 + i) * 2048 + r0 + tx] = f2bf(tile[tx][i]);
}

__global__ __launch_bounds__(256)
void wtrans_kernel(const float* __restrict__ in, u16* __restrict__ out, int R, int C)
{
    __shared__ float tile[32][33];
    const int c0 = blockIdx.x * 32, r0 = blockIdx.y * 32;
    const int tx = threadIdx.x & 31, ty = threadIdx.x >> 5;
    #pragma unroll
    for (int i = ty; i < 32; i += 8)
        tile[i][tx] = in[(size_t)(r0 + i) * C + c0 + tx];
    __syncthreads();
    #pragma unroll
    for (int i = ty; i < 32; i += 8)
        out[(size_t)(c0 + i) * R + r0 + tx] = f2bf(tile[tx][i]);
}

__global__ __launch_bounds__(256)
void kvtrans_kernel(const u16* __restrict__ in, u16* __restrict__ out)
{
    __shared__ u16 tile[32][33];
    const int g = blockIdx.z;
    const int n0 = blockIdx.x * 32, m0 = blockIdx.y * 32;
    const int tx = threadIdx.x & 31, ty = threadIdx.x >> 5;
    #pragma unroll
    for (int i = ty; i < 32; i += 8)
        tile[i][tx] = in[(size_t)(g * 128 + m0 + i) * 2048 + n0 + tx];
    __syncthreads();
    #pragma unroll
    for (int i = ty; i < 32; i += 8)
        out[(size_t)g * 262144 + (size_t)(n0 + i) * 128 + m0 + tx] = tile[tx][i];
}

__global__ __launch_bounds__(256)
void cvt_f32_bf16(const float* __restrict__ in, u16* __restrict__ out)
{
    const long i = ((long)blockIdx.x * 256 + threadIdx.x) * 4;
    float4 v = *(const float4*)(in + i);
    u16x4 o;
    o[0] = f2bf(v.x); o[1] = f2bf(v.y); o[2] = f2bf(v.z); o[3] = f2bf(v.w);
    *(u16x4*)(out + i) = o;
}

// ---------------------------------------------------------------------------
// LayerNorm.  RESF32: resid is f32 (first LN) else bf16.
// FINAL=0: write xb = bf16(LN output); residual chain lives in xb (post-LN).
// FINAL=1: write o1,o2 (f32 d_out x2).
// ---------------------------------------------------------------------------
template<int FINAL, int RESF32>
__global__ __launch_bounds__(256)
void ln_kernel(const void* __restrict__ residv, const u16* __restrict__ add,
               const float* __restrict__ gam, const float* __restrict__ bet,
               u16* __restrict__ xb, float* __restrict__ o1, float* __restrict__ o2)
{
    const long row = blockIdx.x;
    const int  t   = threadIdx.x;
    const long base = row * PD + t * 8;

    u16x8 av = *(const u16x8*)(add + base);
    float y[8];
    if constexpr (RESF32) {
        const float* resid = (const float*)residv;
        float4 r0 = *(const float4*)(resid + base);
        float4 r1 = *(const float4*)(resid + base + 4);
        y[0] = r0.x + bf2f(av[0]); y[1] = r0.y + bf2f(av[1]);
        y[2] = r0.z + bf2f(av[2]); y[3] = r0.w + bf2f(av[3]);
        y[4] = r1.x + bf2f(av[4]); y[5] = r1.y + bf2f(av[5]);
        y[6] = r1.z + bf2f(av[6]); y[7] = r1.w + bf2f(av[7]);
    } else {
        const u16* resid = (const u16*)residv;
        u16x8 rv = *(const u16x8*)(resid + base);
        #pragma unroll
        for (int j = 0; j < 8; j++) y[j] = bf2f(rv[j]) + bf2f(av[j]);
    }

    float s1 = 0.f, s2 = 0.f;
    #pragma unroll
    for (int j = 0; j < 8; j++) { s1 += y[j]; s2 += y[j] * y[j]; }
    #pragma unroll
    for (int d = 1; d < 64; d <<= 1) { s1 += __shfl_xor(s1, d); s2 += __shfl_xor(s2, d); }
    __shared__ float red[8];
    const int w = t >> 6;
    if ((t & 63) == 0) { red[w] = s1; red[4 + w] = s2; }
    __syncthreads();
    s1 = red[0] + red[1] + red[2] + red[3];
    s2 = red[4] + red[5] + red[6] + red[7];
    const float mean = s1 * (1.f / PD);
    const float var  = s2 * (1.f / PD) - mean * mean;
    const float rstd = rsqrtf(var + 1e-5f);

    float4 g0 = *(const float4*)(gam + t * 8);
    float4 g1 = *(const float4*)(gam + t * 8 + 4);
    float4 b0 = *(const float4*)(bet + t * 8);
    float4 b1 = *(const float4*)(bet + t * 8 + 4);
    float gv[8] = {g0.x, g0.y, g0.z, g0.w, g1.x, g1.y, g1.z, g1.w};
    float bv[8] = {b0.x, b0.y, b0.z, b0.w, b1.x, b1.y, b1.z, b1.w};

    float o[8];
    #pragma unroll
    for (int j = 0; j < 8; j++) o[j] = (y[j] - mean) * rstd * gv[j] + bv[j];

    if constexpr (FINAL) {
        float4 p0 = {o[0], o[1], o[2], o[3]}, p1 = {o[4], o[5], o[6], o[7]};
        *(float4*)(o1 + base) = p0; *(float4*)(o1 + base + 4) = p1;
        *(float4*)(o2 + base) = p0; *(float4*)(o2 + base + 4) = p1;
    } else {
        u16x8 ob;
        #pragma unroll
        for (int j = 0; j < 8; j++) ob[j] = f2bf(o[j]);
        *(u16x8*)(xb + base) = ob;
    }
}

__global__ void detect_mask_kernel(const unsigned char* __restrict__ m, int* __restrict__ flag)
{
    __shared__ int s;
    if (threadIdx.x == 0) s = 0;
    __syncthreads();
    int acc = 0;
    for (int i = threadIdx.x; i < 2048; i += 256)
        if (i & 3) acc |= m[i];
    if (acc) atomicOr(&s, 1);
    __syncthreads();
    if (threadIdx.x == 0) *flag = s;
}

// ---------------------------------------------------------------------------
// attn2: per (b,p) group over V=16.  2 waves: wave0 = MFMA scores + masked
// softmax; both waves = PV at n-stride 128.
// ---------------------------------------------------------------------------
__global__ __launch_bounds__(128)
void attn2_kernel(u16* __restrict__ Q, const u16* __restrict__ KV,
                  const void* __restrict__ mask, const int* __restrict__ mflag,
                  float scale)
{
    const int g = blockIdx.x;
    const int b = g >> 7, p = g & 127;
    const int tid  = threadIdx.x;
    const int lane = tid & 63;
    const int w    = tid >> 6;

    const size_t groupbase = ((size_t)(b * 16) * 128 + p) * PD;
    const size_t vstride   = (size_t)128 * PD;

    __shared__ float PL[16][16];

    if (w == 0) {
        const int am   = lane & 15;
        const int koff = (lane >> 4) * 8;
        const u16* qp = Q  + groupbase + (size_t)am * vstride + koff;
        const u16* kp = KV + groupbase + (size_t)am * vstride + koff;

        f32x4 acc = {0.f, 0.f, 0.f, 0.f};
        for (int k0 = 0; k0 < PD; k0 += 32) {
            bf16x8 a  = *(const bf16x8*)(qp + k0);
            bf16x8 bb = *(const bf16x8*)(kp + k0);
            acc = __builtin_amdgcn_mfma_f32_16x16x32_bf16(a, bb, acc, 0, 0, 0);
        }

        const int vk = lane & 15;
        const int hi = lane >> 4;
        const int mf = *mflag;
        float pv[4];
        #pragma unroll
        for (int j = 0; j < 4; j++) {
            const int vq = hi * 4 + j;
            float s = acc[j] * scale;
            const int midx = b * 256 + vq * 16 + vk;
            int msk;
            if (mf) msk = ((const unsigned char*)mask)[midx];
            else    msk = ((const int*)mask)[midx];
            if (msk) s = -1e30f;
            pv[j] = s;
        }
        #pragma unroll
        for (int j = 0; j < 4; j++) {
            float mx = pv[j];
            #pragma unroll
            for (int d = 1; d < 16; d <<= 1) mx = fmaxf(mx, __shfl_xor(mx, d));
            const float e = __expf(pv[j] - mx);
            float sm = e;
            #pragma unroll
            for (int d = 1; d < 16; d <<= 1) sm += __shfl_xor(sm, d);
            pv[j] = e / sm;
        }
        #pragma unroll
        for (int j = 0; j < 4; j++) PL[hi * 4 + j][vk] = pv[j];
    }
    __syncthreads();

    const u16* kvr[16];
    #pragma unroll
    for (int v = 0; v < 16; v++) kvr[v] = KV + groupbase + (size_t)v * vstride;

    for (int vqt = 0; vqt < 16; vqt += 4) {
        float pr[4][16];
        #pragma unroll
        for (int q = 0; q < 4; q++)
            #pragma unroll
            for (int k = 0; k < 16; k++) pr[q][k] = PL[vqt + q][k];
        u16* o0 = Q + groupbase + (size_t)(vqt + 0) * vstride;
        u16* o1 = Q + groupbase + (size_t)(vqt + 1) * vstride;
        u16* o2 = Q + groupbase + (size_t)(vqt + 2) * vstride;
        u16* o3 = Q + groupbase + (size_t)(vqt + 3) * vstride;
        for (int n0 = 0; n0 < PD; n0 += 128) {
            const int n = n0 + tid;
            float a0 = 0.f, a1 = 0.f, a2 = 0.f, a3 = 0.f;
            #pragma unroll
            for (int k = 0; k < 16; k++) {
                const float kvv = bf2f(kvr[k][n]);
                a0 += pr[0][k] * kvv; a1 += pr[1][k] * kvv;
                a2 += pr[2][k] * kvv; a3 += pr[3][k] * kvv;
            }
            o0[n] = f2bf(a0); o1[n] = f2bf(a1); o2[n] = f2bf(a2); o3[n] = f2bf(a3);
        }
    }
}

// ---------------------------------------------------------------------------
extern "C" void kernel_launch(void* const* d_in, const int* in_sizes, int n_in,
                              void* d_out, int out_size, void* d_ws, size_t ws_size,
                              hipStream_t stream)
{
    const float* x0    = (const float*)d_in[0];
    const void*  vmask = d_in[1];
    const float* w_q1  = (const float*)d_in[2];  const float* b_q1  = (const float*)d_in[3];
    const float* w_kv1 = (const float*)d_in[4];  const float* b_kv1 = (const float*)d_in[5];
    const float* w_o1  = (const float*)d_in[6];  const float* b_o1  = (const float*)d_in[7];
    const float* w_q2  = (const float*)d_in[8];  const float* b_q2  = (const float*)d_in[9];
    const float* w_kv2 = (const float*)d_in[10]; const float* b_kv2 = (const float*)d_in[11];
    const float* w_o2  = (const float*)d_in[12]; const float* b_o2  = (const float*)d_in[13];
    const float* g1 = (const float*)d_in[14]; const float* be1 = (const float*)d_in[15];
    const float* g2 = (const float*)d_in[16]; const float* be2 = (const float*)d_in[17];
    const float* g3 = (const float*)d_in[18]; const float* be3 = (const float*)d_in[19];
    const float* w_l1 = (const float*)d_in[20]; const float* b_l1 = (const float*)d_in[21];
    const float* w_l2 = (const float*)d_in[22]; const float* b_l2 = (const float*)d_in[23];

    char* ws = (char*)d_ws;
    size_t off = 0;
    auto alloc = [&](size_t bytes) { size_t o = off; off += (bytes + 255) & ~(size_t)255; return o; };
    const size_t oWQ1  = alloc(8388608),  oWKV1 = alloc(8388608),  oWO1 = alloc(8388608);
    const size_t oWQ2  = alloc(8388608),  oWKV2 = alloc(8388608),  oWO2 = alloc(8388608);
    const size_t oWL1  = alloc(33554432), oWL2  = alloc(33554432);
    const size_t oXB   = alloc(67108864);
    const size_t oQ    = alloc(67108864);   // Q and KV contiguous: FFN hidden reuses both
    const size_t oKV   = alloc(67108864);
    const size_t oKVT  = alloc(67108864);
    const size_t oP1   = alloc(4194304);
    const size_t oFLAG = alloc(256);
    if (ws_size < off) return;

    u16* WQ1T = (u16*)(ws + oWQ1);  u16* WKV1T = (u16*)(ws + oWKV1); u16* WO1T = (u16*)(ws + oWO1);
    u16* WQ2T = (u16*)(ws + oWQ2);  u16* WKV2T = (u16*)(ws + oWKV2); u16* WO2T = (u16*)(ws + oWO2);
    u16* WL1T = (u16*)(ws + oWL1);  u16* WL2T  = (u16*)(ws + oWL2);
    u16* XB   = (u16*)(ws + oXB);   u16* Q     = (u16*)(ws + oQ);
    u16* KV   = (u16*)(ws + oKV);   u16* KVT   = (u16*)(ws + oKVT);
    u16* P1   = (u16*)(ws + oP1);   int* FLAG  = (int*)(ws + oFLAG);
    u16* H    = Q;                  // 128 MB hidden buffer (Q+KV regions)
    u16* F    = KVT;                // FFN output buffer

    const float scale = 0.02209708691f;  // 1/sqrt(2048)
    float* out0 = (float*)d_out;
    float* out1 = out0 + (size_t)NROWS * PD;

    detect_mask_kernel<<<1, 256, 0, stream>>>((const unsigned char*)vmask, FLAG);

    wtrans6_kernel<<<dim3(64, 64, 6), 256, 0, stream>>>(w_q1, w_kv1, w_o1, w_q2, w_kv2, w_o2,
                                                        WQ1T, WKV1T, WO1T, WQ2T, WKV2T, WO2T);
    wtrans_kernel<<<dim3(256, 64), 256, 0, stream>>>(w_l1, WL1T, 2048, 8192);
    wtrans_kernel<<<dim3(64, 256), 256, 0, stream>>>(w_l2, WL2T, 8192, 2048);

    cvt_f32_bf16<<<32768, 256, 0, stream>>>(x0, XB);

    const int BIG = 1 << 30;

    // ---- attn1 ----
    gemm256<0><<<1024, 512, 0, stream>>>(XB, 2048, WQ1T, 2048, Q, KV, 2048, 2048,
                                         b_q1, b_kv1, 2048, 16, 32, 4);
    kvtrans_kernel<<<dim3(64, 4, 128), 256, 0, stream>>>(KV, KVT);
    scores_softmax_kernel<<<128, 256, 0, stream>>>(Q, KV, P1, scale);
    gemm_nt<0,0><<<dim3(1,16,128), 256, 0, stream>>>(P1, 16384, 128, KVT, 262144, 128, Q, 262144, 2048, nullptr, 128, 1.f);
    gemm256<0><<<512, 512, 0, stream>>>(Q, 2048, WO1T, 2048, KV, KV, BIG, 2048,
                                        b_o1, b_o1, 2048, 8, 32, 2);
    ln_kernel<0,1><<<NROWS, 256, 0, stream>>>(x0, KV, g1, be1, XB, nullptr, nullptr);

    // ---- attn2 ----
    gemm256<0><<<1024, 512, 0, stream>>>(XB, 2048, WQ2T, 2048, Q, KV, 2048, 2048,
                                         b_q2, b_kv2, 2048, 16, 32, 4);
    attn2_kernel<<<1024, 128, 0, stream>>>(Q, KV, vmask, FLAG, scale);
    gemm256<0><<<512, 512, 0, stream>>>(Q, 2048, WO2T, 2048, KV, KV, BIG, 2048,
                                        b_o2, b_o2, 2048, 8, 32, 2);
    ln_kernel<0,0><<<NROWS, 256, 0, stream>>>(XB, KV, g2, be2, XB, nullptr, nullptr);

    // ---- FFN: 2 row-chunks of 8192, l1(c) then l2(c) for L3-warm H ----
    for (int c = 0; c < 2; c++) {
        const size_t rows = (size_t)c * 8192;
        gemm256<1><<<1024, 512, 0, stream>>>(XB + rows * 2048, 2048, WL1T, 2048,
                                             H, H, BIG, 8192, b_l1, b_l1, 2048, 32, 32, 4);
        gemm256<0><<<256, 512, 0, stream>>>(H, 8192, WL2T, 8192,
                                            F + rows * 2048, F + rows * 2048, BIG, 2048,
                                            b_l2, b_l2, 8192, 8, 32, 1);
    }
    ln_kernel<1,0><<<NROWS, 256, 0, stream>>>(XB, F, g3, be3, nullptr, out0, out1);
}